// Round 12
// baseline (497.402 us; speedup 1.0000x reference)
//
#include <hip/hip_runtime.h>
#include <math.h>

#define D_DIM 512
#define H_DIM 2048
#define NEXP  8

typedef __bf16 bf16x8 __attribute__((ext_vector_type(8)));
typedef float  f32x4  __attribute__((ext_vector_type(4)));

__device__ __forceinline__ unsigned short f2b(float f) {
    unsigned int u = __float_as_uint(f);
    unsigned int r = (u + 0x7FFFu + ((u >> 16) & 1u)) >> 16;
    return (unsigned short)r;
}

// tanh-form gelu (|err| < 3.3e-4; propagated out-err ~3e-4 vs 1.84e-2 threshold)
__device__ __forceinline__ float gelu_f(float v) {
    float u = v * fmaf(0.044715f * v, v, 1.0f) * 0.7978845608028654f;
    float ex = __expf(2.0f * u);                    // overflow->inf: rcp->0, th->1 (correct)
    float th = fmaf(-2.0f, __builtin_amdgcn_rcpf(ex + 1.0f), 1.0f);
    return 0.5f * v * (1.0f + th);
}

__device__ __forceinline__ void async_cp16(const void* g, void* l) {
    __builtin_amdgcn_global_load_lds(
        (const __attribute__((address_space(1))) unsigned int*)g,
        (__attribute__((address_space(3))) unsigned int*)l, 16, 0, 0);
}

// in [e][R][C] f32 -> out [e][C][R] bf16
__global__ void transpose_conv_kernel(const float* __restrict__ in,
                                      unsigned short* __restrict__ out,
                                      int R, int C) {
    __shared__ unsigned short tile[64][72];
    int e = blockIdx.z;
    const float* ine = in + (size_t)e * R * C;
    unsigned short* oute = out + (size_t)e * C * R;
    int r0 = blockIdx.y * 64, c0 = blockIdx.x * 64;
    int tid = threadIdx.x;
#pragma unroll
    for (int rd = 0; rd < 4; ++rd) {
        int r = (tid >> 4) + rd * 16;
        int c = (tid & 15) * 4;
        float4 v = *(const float4*)&ine[(size_t)(r0 + r) * C + c0 + c];
        tile[c + 0][r] = f2b(v.x);
        tile[c + 1][r] = f2b(v.y);
        tile[c + 2][r] = f2b(v.z);
        tile[c + 3][r] = f2b(v.w);
    }
    __syncthreads();
    int cc = tid >> 2, rc = (tid & 3) * 16;
    unsigned short* op = oute + (size_t)(c0 + cc) * R + r0 + rc;
    *(uint4*)(op)     = *(const uint4*)&tile[cc][rc];
    *(uint4*)(op + 8) = *(const uint4*)&tile[cc][rc + 8];
}

// ---------------- router: top2+softmax + x->bf16 convert (NO atomics) ------
__global__ void router_kernel(const float* __restrict__ x,
                              const float* __restrict__ Wr,
                              float* __restrict__ gate_w,
                              int* __restrict__ route,
                              unsigned short* __restrict__ xbout,
                              int ntok) {
    int wid  = (blockIdx.x * blockDim.x + threadIdx.x) >> 6;
    int lane = threadIdx.x & 63;
    if (wid >= ntok) return;
    const float* xr = x + (size_t)wid * D_DIM;
    float acc[NEXP];
#pragma unroll
    for (int e = 0; e < NEXP; ++e) acc[e] = 0.0f;
#pragma unroll
    for (int it = 0; it < D_DIM / 64; ++it) {
        int d = it * 64 + lane;
        float xv = xr[d];
        if (xbout) xbout[(size_t)wid * D_DIM + d] = f2b(xv);
        const float* wr = Wr + d * NEXP;
#pragma unroll
        for (int e = 0; e < NEXP; ++e) acc[e] = fmaf(xv, wr[e], acc[e]);
    }
#pragma unroll
    for (int off = 32; off >= 1; off >>= 1) {
#pragma unroll
        for (int e = 0; e < NEXP; ++e) acc[e] += __shfl_xor(acc[e], off);
    }
    if (lane == 0) {
        int i0 = 0;
#pragma unroll
        for (int e = 1; e < NEXP; ++e) if (acc[e] > acc[i0]) i0 = e;
        int i1 = (i0 == 0) ? 1 : 0;
#pragma unroll
        for (int e = 0; e < NEXP; ++e) {
            if (e != i0 && acc[e] > acc[i1]) i1 = e;
        }
        float v0 = acc[i0], v1 = acc[i1];
        float ee = expf(v1 - v0);
        float inv = 1.0f / (1.0f + ee);
        int t = wid;
        gate_w[2 * t]     = inv;
        gate_w[2 * t + 1] = ee * inv;
        route[t] = i0 | (i1 << 8);
    }
}

// ---------------- deterministic per-expert stream compaction ---------------
__global__ void lists_kernel(const int* __restrict__ route,
                             int* __restrict__ lists,
                             int* __restrict__ cb,
                             int ntok) {
    __shared__ int wave_off[4];
    int e = blockIdx.x;
    int tid = threadIdx.x;
    int lane = tid & 63, w = tid >> 6;
    int running = 0;
    for (int c0 = 0; c0 < ntok; c0 += 256) {
        int t = c0 + tid;
        int rt = (t < ntok) ? route[t] : -1;
        int e0 = rt & 255, e1 = (rt >> 8) & 255;
        bool p1 = (e1 == e) && (rt >= 0);
        bool p  = ((e0 == e) && (rt >= 0)) || p1;
        unsigned long long mask = __ballot(p);
        int mypos = __popcll(mask & ((1ull << lane) - 1ull));
        int wcnt  = __popcll(mask);
        if (lane == 0) wave_off[w] = wcnt;
        __syncthreads();
        int wbase = 0;
#pragma unroll
        for (int i = 0; i < 4; ++i) if (i < w) wbase += wave_off[i];
        int total = wave_off[0] + wave_off[1] + wave_off[2] + wave_off[3];
        if (p) lists[(size_t)e * ntok + running + wbase + mypos] = 2 * t + (p1 ? 1 : 0);
        running += total;
        __syncthreads();
    }
    if (tid == 0) cb[e] = running;
}

__global__ void prefix_kernel(int* cb) {
    if (threadIdx.x == 0 && blockIdx.x == 0) {
        int s = 0;
#pragma unroll
        for (int e = 0; e < NEXP; ++e) { cb[8 + e] = s; s += cb[e]; }
    }
}

// out[tok] = w0*b2[e0] + w1*b2[e1]
__global__ void bias_gate_kernel(const int* __restrict__ route,
                                 const float* __restrict__ gate_w,
                                 const float* __restrict__ b2,
                                 float* __restrict__ out, int ntok) {
    int t = blockIdx.x * 4 + (threadIdx.x >> 6);
    int lane = threadIdx.x & 63;
    if (t >= ntok) return;
    int rt = route[t];
    int e0 = rt & 255, e1 = (rt >> 8) & 255;
    float w0 = gate_w[2 * t], w1 = gate_w[2 * t + 1];
    const float4* p0 = (const float4*)(b2 + (size_t)e0 * D_DIM);
    const float4* p1 = (const float4*)(b2 + (size_t)e1 * D_DIM);
    float4* po = (float4*)(out + (size_t)t * D_DIM);
#pragma unroll
    for (int j = 0; j < 2; ++j) {
        float4 a = p0[lane * 2 + j], b = p1[lane * 2 + j];
        float4 r;
        r.x = w0 * a.x + w1 * b.x;
        r.y = w0 * a.y + w1 * b.y;
        r.z = w0 * a.z + w1 * b.z;
        r.w = w0 * a.w + w1 * b.w;
        po[lane * 2 + j] = r;
    }
}

// ============ R5-structure 128x128 BK=64 grouped GEMMs, 5 blocks/CU ========
// 4 waves (2Mx2N), wave tile 64x64; single 32KB LDS buffer (EXACTLY 32768B ->
// 5 blocks/CU vs 4 at 33280B); routing arrays read directly from global
// (L2-hot, once per block) instead of LDS. Cross-block TLP is the only
// latency-hiding mechanism in this 2-barrier schedule (R6-R10 ablations),
// so +25% resident blocks is the lever. XOR swizzle; e=bid&7 XCD pin.

// ---------------- pass 1: hdn = gate * gelu(Xg @ W1T^T + b1) ---------------
__global__ __launch_bounds__(256, 5) void gemm1_kernel(
        const unsigned short* __restrict__ xb,    // [ntok][512] bf16
        const unsigned short* __restrict__ W1T,   // [E][2048][512] bf16
        const float* __restrict__ b1,             // [E][2048]
        const float* __restrict__ gate_w,
        const int* __restrict__ lists,
        const int* __restrict__ cb,               // counts[0..7] bases[8..15]
        unsigned short* __restrict__ hdn,         // [2*ntok+256][2048] bf16
        int ntok) {
    int bid = blockIdx.x;
    int e = bid & 7;                 // expert -> XCD pin
    int rest = bid >> 3;
    int ntile = rest & 15;           // 2048/128
    int mt = rest >> 4;
    int cnt = cb[e];
    if (mt * 128 >= cnt) return;
    int base = cb[8 + e];

    __shared__ unsigned short AsBs[16384];   // exactly 32 KB -> 5 blocks/CU
    unsigned short* As = AsBs;
    unsigned short* Bs = AsBs + 8192;

    int tid = threadIdx.x;
    int l = tid & 63, w = tid >> 6;
    int wm = (w & 1) * 64, wn = (w >> 1) * 64;

    const int* listE = lists + (size_t)e * ntok;

    const char* Aglob[4];
    const char* Bglob[4];
    {
        int swz = ((l & 7) ^ (l >> 3)) * 16;
        const char* W1e = (const char*)(W1T + (size_t)e * H_DIM * D_DIM);
#pragma unroll
        for (int c = 0; c < 4; ++c) {
            int row = (w * 4 + c) * 8 + (l >> 3);       // row&7 == l>>3
            int idx = mt * 128 + row;
            int entry = (idx < cnt) ? listE[idx] : -1;
            int tok = (entry >= 0) ? (entry >> 1) : 0;
            Aglob[c] = (const char*)xb + (size_t)tok * 1024 + swz;
            Bglob[c] = W1e + (size_t)(ntile * 128 + row) * 1024 + swz;
        }
    }

    f32x4 acc[4][4];
#pragma unroll
    for (int i = 0; i < 4; ++i)
#pragma unroll
        for (int j = 0; j < 4; ++j) acc[i][j] = (f32x4){0.f, 0.f, 0.f, 0.f};

    for (int kc = 0; kc < 8; ++kc) {
        __syncthreads();          // all waves done reading previous tile
        int ko = kc * 128;
#pragma unroll
        for (int c = 0; c < 4; ++c) {
            async_cp16(Aglob[c] + ko, (char*)As + (w * 4 + c) * 1024);
            async_cp16(Bglob[c] + ko, (char*)Bs + (w * 4 + c) * 1024);
        }
        __syncthreads();          // compiler drains vmcnt(0) before barrier
#pragma unroll
        for (int ks = 0; ks < 2; ++ks) {
            int g = ks * 4 + (l >> 4);
            bf16x8 av[4], bv[4];
#pragma unroll
            for (int mf = 0; mf < 4; ++mf) {
                int m = wm + mf * 16 + (l & 15);
                av[mf] = *(const bf16x8*)((const char*)As + m * 128 + ((g ^ (m & 7)) * 16));
            }
#pragma unroll
            for (int nf = 0; nf < 4; ++nf) {
                int n = wn + nf * 16 + (l & 15);
                bv[nf] = *(const bf16x8*)((const char*)Bs + n * 128 + ((g ^ (n & 7)) * 16));
            }
#pragma unroll
            for (int mf = 0; mf < 4; ++mf)
#pragma unroll
                for (int nf = 0; nf < 4; ++nf)
                    acc[mf][nf] = __builtin_amdgcn_mfma_f32_16x16x32_bf16(
                        av[mf], bv[nf], acc[mf][nf], 0, 0, 0);
        }
    }

    // ---- epilogue: gate/list entries direct from global (L2-hot) ----------
    float twr[4][4];
#pragma unroll
    for (int mf = 0; mf < 4; ++mf) {
#pragma unroll
        for (int r = 0; r < 4; ++r) {
            int row = wm + mf * 16 + (l >> 4) * 4 + r;
            int idx = mt * 128 + row;
            int entry = (idx < cnt) ? listE[idx] : -1;
            twr[mf][r] = (entry >= 0) ? gate_w[entry] : 0.0f;
        }
    }
    const float* b1e = b1 + (size_t)e * H_DIM + ntile * 128;
    float b1v[4];
#pragma unroll
    for (int nf = 0; nf < 4; ++nf)
        b1v[nf] = b1e[wn + nf * 16 + (l & 15)];

    __syncthreads();              // done reading As/Bs -> reuse as out tile
    char* Lo = (char*)AsBs;       // 32 KB out tile: [128 rows][256 B]
#pragma unroll
    for (int mf = 0; mf < 4; ++mf) {
#pragma unroll
        for (int nf = 0; nf < 4; ++nf) {
#pragma unroll
            for (int r = 0; r < 4; ++r) {
                int row = wm + mf * 16 + (l >> 4) * 4 + r;
                int col = wn + nf * 16 + (l & 15);
                float hv = twr[mf][r] * gelu_f(acc[mf][nf][r] + b1v[nf]);
                int byte = row * 256 + ((col * 2) ^ (((row >> 2) & 3) << 5));
                *(unsigned short*)(Lo + byte) = f2b(hv);
            }
        }
    }
    __syncthreads();
#pragma unroll
    for (int j = 0; j < 8; ++j) {
        int row = j * 16 + (tid >> 4);
        int c16 = tid & 15;
        uint4 v = *(const uint4*)(Lo + row * 256 + c16 * 16);
        int colchunk = c16 ^ (((row >> 2) & 3) << 1);
        int gr = mt * 128 + row;
        if (gr < cnt)
            *(uint4*)(hdn + (size_t)(base + gr) * H_DIM + ntile * 128 + colchunk * 8) = v;
    }
}

// ---------------- pass 2: out[tok] += hdn @ W2T^T --------------------------
__global__ __launch_bounds__(256, 5) void gemm2_kernel(
        const unsigned short* __restrict__ hdn,   // [2*ntok+256][2048] bf16
        const unsigned short* __restrict__ W2T,   // [E][512][2048] bf16
        const int* __restrict__ lists,
        const int* __restrict__ cb,
        float* __restrict__ out,
        int ntok) {
    int bid = blockIdx.x;
    int e = bid & 7;                 // expert -> XCD pin
    int rest = bid >> 3;
    int ntile = rest & 3;            // 512/128
    int mt = rest >> 2;
    int cnt = cb[e];
    if (mt * 128 >= cnt) return;
    int base = cb[8 + e];

    __shared__ unsigned short AsBs[16384];   // exactly 32 KB -> 5 blocks/CU
    unsigned short* As = AsBs;
    unsigned short* Bs = AsBs + 8192;

    int tid = threadIdx.x;
    int l = tid & 63, w = tid >> 6;
    int wm = (w & 1) * 64, wn = (w >> 1) * 64;

    const int* listE = lists + (size_t)e * ntok;

    const char* Aglob[4];
    const char* Bglob[4];
    {
        int swz = ((l & 7) ^ (l >> 3)) * 16;
        const char* W2e = (const char*)(W2T + (size_t)e * D_DIM * H_DIM);
#pragma unroll
        for (int c = 0; c < 4; ++c) {
            int row = (w * 4 + c) * 8 + (l >> 3);
            Aglob[c] = (const char*)hdn + (size_t)(base + mt * 128 + row) * 4096 + swz;
            Bglob[c] = W2e + (size_t)(ntile * 128 + row) * 4096 + swz;
        }
    }

    f32x4 acc[4][4];
#pragma unroll
    for (int i = 0; i < 4; ++i)
#pragma unroll
        for (int j = 0; j < 4; ++j) acc[i][j] = (f32x4){0.f, 0.f, 0.f, 0.f};

    for (int kc = 0; kc < 32; ++kc) {
        __syncthreads();
        int ko = kc * 128;
#pragma unroll
        for (int c = 0; c < 4; ++c) {
            async_cp16(Aglob[c] + ko, (char*)As + (w * 4 + c) * 1024);
            async_cp16(Bglob[c] + ko, (char*)Bs + (w * 4 + c) * 1024);
        }
        __syncthreads();
#pragma unroll
        for (int ks = 0; ks < 2; ++ks) {
            int g = ks * 4 + (l >> 4);
            bf16x8 av[4], bv[4];
#pragma unroll
            for (int mf = 0; mf < 4; ++mf) {
                int m = wm + mf * 16 + (l & 15);
                av[mf] = *(const bf16x8*)((const char*)As + m * 128 + ((g ^ (m & 7)) * 16));
            }
#pragma unroll
            for (int nf = 0; nf < 4; ++nf) {
                int n = wn + nf * 16 + (l & 15);
                bv[nf] = *(const bf16x8*)((const char*)Bs + n * 128 + ((g ^ (n & 7)) * 16));
            }
#pragma unroll
            for (int mf = 0; mf < 4; ++mf)
#pragma unroll
                for (int nf = 0; nf < 4; ++nf)
                    acc[mf][nf] = __builtin_amdgcn_mfma_f32_16x16x32_bf16(
                        av[mf], bv[nf], acc[mf][nf], 0, 0, 0);
        }
    }

    // epilogue: masked atomic scatter; token ids direct from lists (L2-hot)
#pragma unroll
    for (int mf = 0; mf < 4; ++mf) {
#pragma unroll
        for (int r = 0; r < 4; ++r) {
            int rl = wm + mf * 16 + (l >> 4) * 4 + r;
            int gr = mt * 128 + rl;
            if (gr < cnt) {
                int entry = listE[gr];
                int tok = entry >> 1;
                float* op = out + (size_t)tok * D_DIM + ntile * 128 + wn;
#pragma unroll
                for (int nf = 0; nf < 4; ++nf)
                    atomicAdd(op + nf * 16 + (l & 15), acc[mf][nf][r]);
            }
        }
    }
}

// ================= fused fallback (small workspace) ========================
#define FBT 64
#define FKC 64
#define FHC 64
#define FTPB 512

__global__ __launch_bounds__(FTPB) void moe_fused_fallback(
        const float* __restrict__ x,
        const float* __restrict__ W1, const float* __restrict__ b1,
        const float* __restrict__ W2, const float* __restrict__ b2,
        const float* __restrict__ gate_w,
        const int* __restrict__ lists, const int* __restrict__ counts,
        float* __restrict__ out, int ntok, int tiles) {
    __shared__ __align__(16) float ldsA[FBT][FKC + 4];
    __shared__ __align__(16) float ldsB[FKC][FHC + 4];
    __shared__ int   toks[FBT];
    __shared__ float tw[FBT];
    int e = blockIdx.x / tiles;
    int tile = blockIdx.x % tiles;
    int cnt = counts[e];
    if (tile * FBT >= cnt) return;
    int tid = threadIdx.x;
    int srow = tid >> 3, scol = (tid & 7) * 8;
    int tg2 = tid >> 4, sg4 = tid & 15;
    if (tid < FBT) {
        int idx = tile * FBT + tid;
        int entry = (idx < cnt) ? lists[(size_t)e * ntok + idx] : -1;
        toks[tid] = (entry >= 0) ? (entry >> 1) : 0;
        tw[tid]   = (entry >= 0) ? gate_w[entry] : 0.0f;
    }
    __syncthreads();
    float yacc[2][32];
#pragma unroll
    for (int p = 0; p < 2; ++p)
#pragma unroll
        for (int i = 0; i < 32; ++i) yacc[p][i] = 0.0f;
    const float* W1e = W1 + (size_t)e * D_DIM * H_DIM;
    const float* W2e = W2 + (size_t)e * H_DIM * D_DIM;
    const float* b1e = b1 + (size_t)e * H_DIM;
    int t0 = tg2, t1 = tg2 + 32;
    for (int hc = 0; hc < H_DIM / FHC; ++hc) {
        float pre[2][4];
#pragma unroll
        for (int p = 0; p < 2; ++p)
#pragma unroll
            for (int j = 0; j < 4; ++j) pre[p][j] = 0.0f;
        for (int kc = 0; kc < D_DIM / FKC; ++kc) {
            __syncthreads();
            {
                const float* src = x + (size_t)toks[srow] * D_DIM + kc * FKC + scol;
                *(float4*)&ldsA[srow][scol]     = *(const float4*)(src);
                *(float4*)&ldsA[srow][scol + 4] = *(const float4*)(src + 4);
                const float* ws1 = W1e + (size_t)(kc * FKC + srow) * H_DIM + hc * FHC + scol;
                *(float4*)&ldsB[srow][scol]     = *(const float4*)(ws1);
                *(float4*)&ldsB[srow][scol + 4] = *(const float4*)(ws1 + 4);
            }
            __syncthreads();
#pragma unroll
            for (int k = 0; k < FKC; ++k) {
                float a0 = ldsA[t0][k], a1 = ldsA[t1][k];
                const float4 b4 = *(const float4*)&ldsB[k][sg4 * 4];
                pre[0][0] = fmaf(a0, b4.x, pre[0][0]);
                pre[0][1] = fmaf(a0, b4.y, pre[0][1]);
                pre[0][2] = fmaf(a0, b4.z, pre[0][2]);
                pre[0][3] = fmaf(a0, b4.w, pre[0][3]);
                pre[1][0] = fmaf(a1, b4.x, pre[1][0]);
                pre[1][1] = fmaf(a1, b4.y, pre[1][1]);
                pre[1][2] = fmaf(a1, b4.z, pre[1][2]);
                pre[1][3] = fmaf(a1, b4.w, pre[1][3]);
            }
        }
        __syncthreads();
        {
            const float* b1p = b1e + hc * FHC + sg4 * 4;
            float4 h0, h1;
            h0.x = gelu_f(pre[0][0] + b1p[0]); h0.y = gelu_f(pre[0][1] + b1p[1]);
            h0.z = gelu_f(pre[0][2] + b1p[2]); h0.w = gelu_f(pre[0][3] + b1p[3]);
            h1.x = gelu_f(pre[1][0] + b1p[0]); h1.y = gelu_f(pre[1][1] + b1p[1]);
            h1.z = gelu_f(pre[1][2] + b1p[2]); h1.w = gelu_f(pre[1][3] + b1p[3]);
            *(float4*)&ldsA[t0][sg4 * 4] = h0;
            *(float4*)&ldsA[t1][sg4 * 4] = h1;
        }
        for (int dt = 0; dt < 8; ++dt) {
            __syncthreads();
            {
                const float* ws2 = W2e + (size_t)(hc * FHC + srow) * D_DIM + dt * 64 + scol;
                *(float4*)&ldsB[srow][scol]     = *(const float4*)(ws2);
                *(float4*)&ldsB[srow][scol + 4] = *(const float4*)(ws2 + 4);
            }
            __syncthreads();
#pragma unroll
            for (int hh = 0; hh < FHC; ++hh) {
                float a0 = ldsA[t0][hh], a1 = ldsA[t1][hh];
                const float4 b4 = *(const float4*)&ldsB[hh][sg4 * 4];
                yacc[0][dt * 4 + 0] = fmaf(a0, b4.x, yacc[0][dt * 4 + 0]);
                yacc[0][dt * 4 + 1] = fmaf(a0, b4.y, yacc[0][dt * 4 + 1]);
                yacc[0][dt * 4 + 2] = fmaf(a0, b4.z, yacc[0][dt * 4 + 2]);
                yacc[0][dt * 4 + 3] = fmaf(a0, b4.w, yacc[0][dt * 4 + 3]);
                yacc[1][dt * 4 + 0] = fmaf(a1, b4.x, yacc[1][dt * 4 + 0]);
                yacc[1][dt * 4 + 1] = fmaf(a1, b4.y, yacc[1][dt * 4 + 1]);
                yacc[1][dt * 4 + 2] = fmaf(a1, b4.z, yacc[1][dt * 4 + 2]);
                yacc[1][dt * 4 + 3] = fmaf(a1, b4.w, yacc[1][dt * 4 + 3]);
            }
        }
    }
    const float* b2e = b2 + (size_t)e * D_DIM;
#pragma unroll
    for (int p = 0; p < 2; ++p) {
        int slot = (p == 0) ? t0 : t1;
        if (tile * FBT + slot < cnt) {
            float wv = tw[slot];
            float* op = out + (size_t)toks[slot] * D_DIM;
#pragma unroll
            for (int dt = 0; dt < 8; ++dt)
#pragma unroll
                for (int j = 0; j < 4; ++j) {
                    int d = dt * 64 + sg4 * 4 + j;
                    atomicAdd(&op[d], wv * (yacc[p][dt * 4 + j] + b2e[d]));
                }
        }
    }
}

// ===========================================================================
extern "C" void kernel_launch(void* const* d_in, const int* in_sizes, int n_in,
                              void* d_out, int out_size, void* d_ws, size_t ws_size,
                              hipStream_t stream) {
    const float* x  = (const float*)d_in[0];
    const float* Wr = (const float*)d_in[1];
    const float* W1 = (const float*)d_in[2];
    const float* b1 = (const float*)d_in[3];
    const float* W2 = (const float*)d_in[4];
    const float* b2 = (const float*)d_in[5];
    float* out = (float*)d_out;
    int ntok = in_sizes[0] / D_DIM;   // 16384

    size_t off_route = 1024;
    size_t off_gate  = off_route + (size_t)ntok * 4;
    size_t off_lists = off_gate + (size_t)2 * ntok * 4;
    size_t off_xb    = off_lists + (size_t)NEXP * ntok * 4;
    size_t off_w1t   = off_xb + (size_t)ntok * D_DIM * 2;
    size_t off_w2t   = off_w1t + (size_t)NEXP * D_DIM * H_DIM * 2;
    size_t off_hdn   = off_w2t + (size_t)NEXP * D_DIM * H_DIM * 2;
    size_t need      = off_hdn + (size_t)(2 * ntok + 256) * H_DIM * 2;  // +slack

    int*   cb     = (int*)d_ws;
    int*   route  = (int*)((char*)d_ws + off_route);
    float* gate_w = (float*)((char*)d_ws + off_gate);
    int*   lists  = (int*)((char*)d_ws + off_lists);

    if (ws_size >= need) {
        unsigned short* xb  = (unsigned short*)((char*)d_ws + off_xb);
        unsigned short* W1T = (unsigned short*)((char*)d_ws + off_w1t);
        unsigned short* W2T = (unsigned short*)((char*)d_ws + off_w2t);
        unsigned short* hdn = (unsigned short*)((char*)d_ws + off_hdn);

        transpose_conv_kernel<<<dim3(H_DIM / 64, D_DIM / 64, NEXP), 256, 0, stream>>>(
            W1, W1T, D_DIM, H_DIM);
        transpose_conv_kernel<<<dim3(D_DIM / 64, H_DIM / 64, NEXP), 256, 0, stream>>>(
            W2, W2T, H_DIM, D_DIM);
        router_kernel<<<(ntok + 3) / 4, 256, 0, stream>>>(
            x, Wr, gate_w, route, xb, ntok);
        lists_kernel<<<NEXP, 256, 0, stream>>>(route, lists, cb, ntok);
        prefix_kernel<<<1, 64, 0, stream>>>(cb);
        bias_gate_kernel<<<(ntok + 3) / 4, 256, 0, stream>>>(
            route, gate_w, b2, out, ntok);
        int mtiles = ntok / 128;   // 128
        gemm1_kernel<<<NEXP * 16 * mtiles, 256, 0, stream>>>(
            xb, W1T, b1, gate_w, lists, cb, hdn, ntok);
        gemm2_kernel<<<NEXP * 4 * mtiles, 256, 0, stream>>>(
            hdn, W2T, lists, cb, out, ntok);
    } else {
        hipMemsetAsync(d_out, 0, (size_t)out_size * sizeof(float), stream);
        router_kernel<<<(ntok + 3) / 4, 256, 0, stream>>>(
            x, Wr, gate_w, route, (unsigned short*)0, ntok);
        lists_kernel<<<NEXP, 256, 0, stream>>>(route, lists, cb, ntok);
        prefix_kernel<<<1, 64, 0, stream>>>(cb);
        int tiles = (ntok + FBT - 1) / FBT;
        moe_fused_fallback<<<NEXP * tiles, FTPB, 0, stream>>>(
            x, W1, b1, W2, b2, gate_w, lists, cb, out, ntok, tiles);
    }
}

// Round 13
// 316.061 us; speedup vs baseline: 1.5738x; 1.5738x over previous
//
#include <hip/hip_runtime.h>
#include <math.h>

#define D_DIM 512
#define H_DIM 2048
#define NEXP  8

typedef __bf16 bf16x8 __attribute__((ext_vector_type(8)));
typedef float  f32x4  __attribute__((ext_vector_type(4)));

__device__ __forceinline__ unsigned short f2b(float f) {
    unsigned int u = __float_as_uint(f);
    unsigned int r = (u + 0x7FFFu + ((u >> 16) & 1u)) >> 16;
    return (unsigned short)r;
}

// tanh-form gelu (|err| < 3.3e-4; propagated out-err ~3e-4 vs 1.84e-2 threshold)
__device__ __forceinline__ float gelu_f(float v) {
    float u = v * fmaf(0.044715f * v, v, 1.0f) * 0.7978845608028654f;
    float ex = __expf(2.0f * u);                    // overflow->inf: rcp->0, th->1 (correct)
    float th = fmaf(-2.0f, __builtin_amdgcn_rcpf(ex + 1.0f), 1.0f);
    return 0.5f * v * (1.0f + th);
}

__device__ __forceinline__ void async_cp16(const void* g, void* l) {
    __builtin_amdgcn_global_load_lds(
        (const __attribute__((address_space(1))) unsigned int*)g,
        (__attribute__((address_space(3))) unsigned int*)l, 16, 0, 0);
}

// in [e][R][C] f32 -> out [e][C][R] bf16
__global__ void transpose_conv_kernel(const float* __restrict__ in,
                                      unsigned short* __restrict__ out,
                                      int R, int C) {
    __shared__ unsigned short tile[64][72];
    int e = blockIdx.z;
    const float* ine = in + (size_t)e * R * C;
    unsigned short* oute = out + (size_t)e * C * R;
    int r0 = blockIdx.y * 64, c0 = blockIdx.x * 64;
    int tid = threadIdx.x;
#pragma unroll
    for (int rd = 0; rd < 4; ++rd) {
        int r = (tid >> 4) + rd * 16;
        int c = (tid & 15) * 4;
        float4 v = *(const float4*)&ine[(size_t)(r0 + r) * C + c0 + c];
        tile[c + 0][r] = f2b(v.x);
        tile[c + 1][r] = f2b(v.y);
        tile[c + 2][r] = f2b(v.z);
        tile[c + 3][r] = f2b(v.w);
    }
    __syncthreads();
    int cc = tid >> 2, rc = (tid & 3) * 16;
    unsigned short* op = oute + (size_t)(c0 + cc) * R + r0 + rc;
    *(uint4*)(op)     = *(const uint4*)&tile[cc][rc];
    *(uint4*)(op + 8) = *(const uint4*)&tile[cc][rc + 8];
}

// ---------------- router: top2+softmax + x->bf16 convert (NO atomics) ------
__global__ void router_kernel(const float* __restrict__ x,
                              const float* __restrict__ Wr,
                              float* __restrict__ gate_w,
                              int* __restrict__ route,
                              unsigned short* __restrict__ xbout,
                              int ntok) {
    int wid  = (blockIdx.x * blockDim.x + threadIdx.x) >> 6;
    int lane = threadIdx.x & 63;
    if (wid >= ntok) return;
    const float* xr = x + (size_t)wid * D_DIM;
    float acc[NEXP];
#pragma unroll
    for (int e = 0; e < NEXP; ++e) acc[e] = 0.0f;
#pragma unroll
    for (int it = 0; it < D_DIM / 64; ++it) {
        int d = it * 64 + lane;
        float xv = xr[d];
        if (xbout) xbout[(size_t)wid * D_DIM + d] = f2b(xv);
        const float* wr = Wr + d * NEXP;
#pragma unroll
        for (int e = 0; e < NEXP; ++e) acc[e] = fmaf(xv, wr[e], acc[e]);
    }
#pragma unroll
    for (int off = 32; off >= 1; off >>= 1) {
#pragma unroll
        for (int e = 0; e < NEXP; ++e) acc[e] += __shfl_xor(acc[e], off);
    }
    if (lane == 0) {
        int i0 = 0;
#pragma unroll
        for (int e = 1; e < NEXP; ++e) if (acc[e] > acc[i0]) i0 = e;
        int i1 = (i0 == 0) ? 1 : 0;
#pragma unroll
        for (int e = 0; e < NEXP; ++e) {
            if (e != i0 && acc[e] > acc[i1]) i1 = e;
        }
        float v0 = acc[i0], v1 = acc[i1];
        float ee = expf(v1 - v0);
        float inv = 1.0f / (1.0f + ee);
        int t = wid;
        gate_w[2 * t]     = inv;
        gate_w[2 * t + 1] = ee * inv;
        route[t] = i0 | (i1 << 8);
    }
}

// ---------------- deterministic per-expert stream compaction ---------------
__global__ void lists_kernel(const int* __restrict__ route,
                             int* __restrict__ lists,
                             int* __restrict__ cb,
                             int ntok) {
    __shared__ int wave_off[4];
    int e = blockIdx.x;
    int tid = threadIdx.x;
    int lane = tid & 63, w = tid >> 6;
    int running = 0;
    for (int c0 = 0; c0 < ntok; c0 += 256) {
        int t = c0 + tid;
        int rt = (t < ntok) ? route[t] : -1;
        int e0 = rt & 255, e1 = (rt >> 8) & 255;
        bool p1 = (e1 == e) && (rt >= 0);
        bool p  = ((e0 == e) && (rt >= 0)) || p1;
        unsigned long long mask = __ballot(p);
        int mypos = __popcll(mask & ((1ull << lane) - 1ull));
        int wcnt  = __popcll(mask);
        if (lane == 0) wave_off[w] = wcnt;
        __syncthreads();
        int wbase = 0;
#pragma unroll
        for (int i = 0; i < 4; ++i) if (i < w) wbase += wave_off[i];
        int total = wave_off[0] + wave_off[1] + wave_off[2] + wave_off[3];
        if (p) lists[(size_t)e * ntok + running + wbase + mypos] = 2 * t + (p1 ? 1 : 0);
        running += total;
        __syncthreads();
    }
    if (tid == 0) cb[e] = running;
}

__global__ void prefix_kernel(int* cb) {
    if (threadIdx.x == 0 && blockIdx.x == 0) {
        int s = 0;
#pragma unroll
        for (int e = 0; e < NEXP; ++e) { cb[8 + e] = s; s += cb[e]; }
    }
}

// out[tok] = w0*b2[e0] + w1*b2[e1]
__global__ void bias_gate_kernel(const int* __restrict__ route,
                                 const float* __restrict__ gate_w,
                                 const float* __restrict__ b2,
                                 float* __restrict__ out, int ntok) {
    int t = blockIdx.x * 4 + (threadIdx.x >> 6);
    int lane = threadIdx.x & 63;
    if (t >= ntok) return;
    int rt = route[t];
    int e0 = rt & 255, e1 = (rt >> 8) & 255;
    float w0 = gate_w[2 * t], w1 = gate_w[2 * t + 1];
    const float4* p0 = (const float4*)(b2 + (size_t)e0 * D_DIM);
    const float4* p1 = (const float4*)(b2 + (size_t)e1 * D_DIM);
    float4* po = (float4*)(out + (size_t)t * D_DIM);
#pragma unroll
    for (int j = 0; j < 2; ++j) {
        float4 a = p0[lane * 2 + j], b = p1[lane * 2 + j];
        float4 r;
        r.x = w0 * a.x + w1 * b.x;
        r.y = w0 * a.y + w1 * b.y;
        r.z = w0 * a.z + w1 * b.z;
        r.w = w0 * a.w + w1 * b.w;
        po[lane * 2 + j] = r;
    }
}

// ============ R5-structure 128x128 BK=64 grouped GEMMs, 5 blocks/CU ========
// 4 waves (2Mx2N), wave tile 64x64; LDS EXACTLY 32768B -> HW fits 5 blocks/CU
// (vs 4 at 33280B). __launch_bounds__(256,4): R12's (256,5) capped regalloc
// at 48 VGPR -> acc spilled to scratch (WRITE 65.5->78MB, 2x slower). The
// 2nd arg only constrains the ALLOCATOR; at the natural 60-64 VGPR (<=64 ->
// 8 waves/SIMD budget, m69) hardware occupancy is LDS-limited = 5 blocks.
// Routing arrays read from global (L2-hot) instead of LDS. XOR swizzle;
// e=bid&7 XCD pin.

// ---------------- pass 1: hdn = gate * gelu(Xg @ W1T^T + b1) ---------------
__global__ __launch_bounds__(256, 4) void gemm1_kernel(
        const unsigned short* __restrict__ xb,    // [ntok][512] bf16
        const unsigned short* __restrict__ W1T,   // [E][2048][512] bf16
        const float* __restrict__ b1,             // [E][2048]
        const float* __restrict__ gate_w,
        const int* __restrict__ lists,
        const int* __restrict__ cb,               // counts[0..7] bases[8..15]
        unsigned short* __restrict__ hdn,         // [2*ntok+256][2048] bf16
        int ntok) {
    int bid = blockIdx.x;
    int e = bid & 7;                 // expert -> XCD pin
    int rest = bid >> 3;
    int ntile = rest & 15;           // 2048/128
    int mt = rest >> 4;
    int cnt = cb[e];
    if (mt * 128 >= cnt) return;
    int base = cb[8 + e];

    __shared__ unsigned short AsBs[16384];   // exactly 32 KB
    unsigned short* As = AsBs;
    unsigned short* Bs = AsBs + 8192;

    int tid = threadIdx.x;
    int l = tid & 63, w = tid >> 6;
    int wm = (w & 1) * 64, wn = (w >> 1) * 64;

    const int* listE = lists + (size_t)e * ntok;

    const char* Aglob[4];
    const char* Bglob[4];
    {
        int swz = ((l & 7) ^ (l >> 3)) * 16;
        const char* W1e = (const char*)(W1T + (size_t)e * H_DIM * D_DIM);
#pragma unroll
        for (int c = 0; c < 4; ++c) {
            int row = (w * 4 + c) * 8 + (l >> 3);       // row&7 == l>>3
            int idx = mt * 128 + row;
            int entry = (idx < cnt) ? listE[idx] : -1;
            int tok = (entry >= 0) ? (entry >> 1) : 0;
            Aglob[c] = (const char*)xb + (size_t)tok * 1024 + swz;
            Bglob[c] = W1e + (size_t)(ntile * 128 + row) * 1024 + swz;
        }
    }

    f32x4 acc[4][4];
#pragma unroll
    for (int i = 0; i < 4; ++i)
#pragma unroll
        for (int j = 0; j < 4; ++j) acc[i][j] = (f32x4){0.f, 0.f, 0.f, 0.f};

    for (int kc = 0; kc < 8; ++kc) {
        __syncthreads();          // all waves done reading previous tile
        int ko = kc * 128;
#pragma unroll
        for (int c = 0; c < 4; ++c) {
            async_cp16(Aglob[c] + ko, (char*)As + (w * 4 + c) * 1024);
            async_cp16(Bglob[c] + ko, (char*)Bs + (w * 4 + c) * 1024);
        }
        __syncthreads();          // compiler drains vmcnt(0) before barrier
#pragma unroll
        for (int ks = 0; ks < 2; ++ks) {
            int g = ks * 4 + (l >> 4);
            bf16x8 av[4], bv[4];
#pragma unroll
            for (int mf = 0; mf < 4; ++mf) {
                int m = wm + mf * 16 + (l & 15);
                av[mf] = *(const bf16x8*)((const char*)As + m * 128 + ((g ^ (m & 7)) * 16));
            }
#pragma unroll
            for (int nf = 0; nf < 4; ++nf) {
                int n = wn + nf * 16 + (l & 15);
                bv[nf] = *(const bf16x8*)((const char*)Bs + n * 128 + ((g ^ (n & 7)) * 16));
            }
#pragma unroll
            for (int mf = 0; mf < 4; ++mf)
#pragma unroll
                for (int nf = 0; nf < 4; ++nf)
                    acc[mf][nf] = __builtin_amdgcn_mfma_f32_16x16x32_bf16(
                        av[mf], bv[nf], acc[mf][nf], 0, 0, 0);
        }
    }

    // ---- epilogue: gate/list entries direct from global (L2-hot) ----------
    float twr[4][4];
#pragma unroll
    for (int mf = 0; mf < 4; ++mf) {
#pragma unroll
        for (int r = 0; r < 4; ++r) {
            int row = wm + mf * 16 + (l >> 4) * 4 + r;
            int idx = mt * 128 + row;
            int entry = (idx < cnt) ? listE[idx] : -1;
            twr[mf][r] = (entry >= 0) ? gate_w[entry] : 0.0f;
        }
    }
    const float* b1e = b1 + (size_t)e * H_DIM + ntile * 128;
    float b1v[4];
#pragma unroll
    for (int nf = 0; nf < 4; ++nf)
        b1v[nf] = b1e[wn + nf * 16 + (l & 15)];

    __syncthreads();              // done reading As/Bs -> reuse as out tile
    char* Lo = (char*)AsBs;       // 32 KB out tile: [128 rows][256 B]
#pragma unroll
    for (int mf = 0; mf < 4; ++mf) {
#pragma unroll
        for (int nf = 0; nf < 4; ++nf) {
#pragma unroll
            for (int r = 0; r < 4; ++r) {
                int row = wm + mf * 16 + (l >> 4) * 4 + r;
                int col = wn + nf * 16 + (l & 15);
                float hv = twr[mf][r] * gelu_f(acc[mf][nf][r] + b1v[nf]);
                int byte = row * 256 + ((col * 2) ^ (((row >> 2) & 3) << 5));
                *(unsigned short*)(Lo + byte) = f2b(hv);
            }
        }
    }
    __syncthreads();
#pragma unroll
    for (int j = 0; j < 8; ++j) {
        int row = j * 16 + (tid >> 4);
        int c16 = tid & 15;
        uint4 v = *(const uint4*)(Lo + row * 256 + c16 * 16);
        int colchunk = c16 ^ (((row >> 2) & 3) << 1);
        int gr = mt * 128 + row;
        if (gr < cnt)
            *(uint4*)(hdn + (size_t)(base + gr) * H_DIM + ntile * 128 + colchunk * 8) = v;
    }
}

// ---------------- pass 2: out[tok] += hdn @ W2T^T --------------------------
__global__ __launch_bounds__(256, 4) void gemm2_kernel(
        const unsigned short* __restrict__ hdn,   // [2*ntok+256][2048] bf16
        const unsigned short* __restrict__ W2T,   // [E][512][2048] bf16
        const int* __restrict__ lists,
        const int* __restrict__ cb,
        float* __restrict__ out,
        int ntok) {
    int bid = blockIdx.x;
    int e = bid & 7;                 // expert -> XCD pin
    int rest = bid >> 3;
    int ntile = rest & 3;            // 512/128
    int mt = rest >> 2;
    int cnt = cb[e];
    if (mt * 128 >= cnt) return;
    int base = cb[8 + e];

    __shared__ unsigned short AsBs[16384];   // exactly 32 KB
    unsigned short* As = AsBs;
    unsigned short* Bs = AsBs + 8192;

    int tid = threadIdx.x;
    int l = tid & 63, w = tid >> 6;
    int wm = (w & 1) * 64, wn = (w >> 1) * 64;

    const int* listE = lists + (size_t)e * ntok;

    const char* Aglob[4];
    const char* Bglob[4];
    {
        int swz = ((l & 7) ^ (l >> 3)) * 16;
        const char* W2e = (const char*)(W2T + (size_t)e * D_DIM * H_DIM);
#pragma unroll
        for (int c = 0; c < 4; ++c) {
            int row = (w * 4 + c) * 8 + (l >> 3);
            Aglob[c] = (const char*)hdn + (size_t)(base + mt * 128 + row) * 4096 + swz;
            Bglob[c] = W2e + (size_t)(ntile * 128 + row) * 4096 + swz;
        }
    }

    f32x4 acc[4][4];
#pragma unroll
    for (int i = 0; i < 4; ++i)
#pragma unroll
        for (int j = 0; j < 4; ++j) acc[i][j] = (f32x4){0.f, 0.f, 0.f, 0.f};

    for (int kc = 0; kc < 32; ++kc) {
        __syncthreads();
        int ko = kc * 128;
#pragma unroll
        for (int c = 0; c < 4; ++c) {
            async_cp16(Aglob[c] + ko, (char*)As + (w * 4 + c) * 1024);
            async_cp16(Bglob[c] + ko, (char*)Bs + (w * 4 + c) * 1024);
        }
        __syncthreads();
#pragma unroll
        for (int ks = 0; ks < 2; ++ks) {
            int g = ks * 4 + (l >> 4);
            bf16x8 av[4], bv[4];
#pragma unroll
            for (int mf = 0; mf < 4; ++mf) {
                int m = wm + mf * 16 + (l & 15);
                av[mf] = *(const bf16x8*)((const char*)As + m * 128 + ((g ^ (m & 7)) * 16));
            }
#pragma unroll
            for (int nf = 0; nf < 4; ++nf) {
                int n = wn + nf * 16 + (l & 15);
                bv[nf] = *(const bf16x8*)((const char*)Bs + n * 128 + ((g ^ (n & 7)) * 16));
            }
#pragma unroll
            for (int mf = 0; mf < 4; ++mf)
#pragma unroll
                for (int nf = 0; nf < 4; ++nf)
                    acc[mf][nf] = __builtin_amdgcn_mfma_f32_16x16x32_bf16(
                        av[mf], bv[nf], acc[mf][nf], 0, 0, 0);
        }
    }

    // epilogue: masked atomic scatter; token ids direct from lists (L2-hot)
#pragma unroll
    for (int mf = 0; mf < 4; ++mf) {
#pragma unroll
        for (int r = 0; r < 4; ++r) {
            int rl = wm + mf * 16 + (l >> 4) * 4 + r;
            int gr = mt * 128 + rl;
            if (gr < cnt) {
                int entry = listE[gr];
                int tok = entry >> 1;
                float* op = out + (size_t)tok * D_DIM + ntile * 128 + wn;
#pragma unroll
                for (int nf = 0; nf < 4; ++nf)
                    atomicAdd(op + nf * 16 + (l & 15), acc[mf][nf][r]);
            }
        }
    }
}

// ================= fused fallback (small workspace) ========================
#define FBT 64
#define FKC 64
#define FHC 64
#define FTPB 512

__global__ __launch_bounds__(FTPB) void moe_fused_fallback(
        const float* __restrict__ x,
        const float* __restrict__ W1, const float* __restrict__ b1,
        const float* __restrict__ W2, const float* __restrict__ b2,
        const float* __restrict__ gate_w,
        const int* __restrict__ lists, const int* __restrict__ counts,
        float* __restrict__ out, int ntok, int tiles) {
    __shared__ __align__(16) float ldsA[FBT][FKC + 4];
    __shared__ __align__(16) float ldsB[FKC][FHC + 4];
    __shared__ int   toks[FBT];
    __shared__ float tw[FBT];
    int e = blockIdx.x / tiles;
    int tile = blockIdx.x % tiles;
    int cnt = counts[e];
    if (tile * FBT >= cnt) return;
    int tid = threadIdx.x;
    int srow = tid >> 3, scol = (tid & 7) * 8;
    int tg2 = tid >> 4, sg4 = tid & 15;
    if (tid < FBT) {
        int idx = tile * FBT + tid;
        int entry = (idx < cnt) ? lists[(size_t)e * ntok + idx] : -1;
        toks[tid] = (entry >= 0) ? (entry >> 1) : 0;
        tw[tid]   = (entry >= 0) ? gate_w[entry] : 0.0f;
    }
    __syncthreads();
    float yacc[2][32];
#pragma unroll
    for (int p = 0; p < 2; ++p)
#pragma unroll
        for (int i = 0; i < 32; ++i) yacc[p][i] = 0.0f;
    const float* W1e = W1 + (size_t)e * D_DIM * H_DIM;
    const float* W2e = W2 + (size_t)e * H_DIM * D_DIM;
    const float* b1e = b1 + (size_t)e * H_DIM;
    int t0 = tg2, t1 = tg2 + 32;
    for (int hc = 0; hc < H_DIM / FHC; ++hc) {
        float pre[2][4];
#pragma unroll
        for (int p = 0; p < 2; ++p)
#pragma unroll
            for (int j = 0; j < 4; ++j) pre[p][j] = 0.0f;
        for (int kc = 0; kc < D_DIM / FKC; ++kc) {
            __syncthreads();
            {
                const float* src = x + (size_t)toks[srow] * D_DIM + kc * FKC + scol;
                *(float4*)&ldsA[srow][scol]     = *(const float4*)(src);
                *(float4*)&ldsA[srow][scol + 4] = *(const float4*)(src + 4);
                const float* ws1 = W1e + (size_t)(kc * FKC + srow) * H_DIM + hc * FHC + scol;
                *(float4*)&ldsB[srow][scol]     = *(const float4*)(ws1);
                *(float4*)&ldsB[srow][scol + 4] = *(const float4*)(ws1 + 4);
            }
            __syncthreads();
#pragma unroll
            for (int k = 0; k < FKC; ++k) {
                float a0 = ldsA[t0][k], a1 = ldsA[t1][k];
                const float4 b4 = *(const float4*)&ldsB[k][sg4 * 4];
                pre[0][0] = fmaf(a0, b4.x, pre[0][0]);
                pre[0][1] = fmaf(a0, b4.y, pre[0][1]);
                pre[0][2] = fmaf(a0, b4.z, pre[0][2]);
                pre[0][3] = fmaf(a0, b4.w, pre[0][3]);
                pre[1][0] = fmaf(a1, b4.x, pre[1][0]);
                pre[1][1] = fmaf(a1, b4.y, pre[1][1]);
                pre[1][2] = fmaf(a1, b4.z, pre[1][2]);
                pre[1][3] = fmaf(a1, b4.w, pre[1][3]);
            }
        }
        __syncthreads();
        {
            const float* b1p = b1e + hc * FHC + sg4 * 4;
            float4 h0, h1;
            h0.x = gelu_f(pre[0][0] + b1p[0]); h0.y = gelu_f(pre[0][1] + b1p[1]);
            h0.z = gelu_f(pre[0][2] + b1p[2]); h0.w = gelu_f(pre[0][3] + b1p[3]);
            h1.x = gelu_f(pre[1][0] + b1p[0]); h1.y = gelu_f(pre[1][1] + b1p[1]);
            h1.z = gelu_f(pre[1][2] + b1p[2]); h1.w = gelu_f(pre[1][3] + b1p[3]);
            *(float4*)&ldsA[t0][sg4 * 4] = h0;
            *(float4*)&ldsA[t1][sg4 * 4] = h1;
        }
        for (int dt = 0; dt < 8; ++dt) {
            __syncthreads();
            {
                const float* ws2 = W2e + (size_t)(hc * FHC + srow) * D_DIM + dt * 64 + scol;
                *(float4*)&ldsB[srow][scol]     = *(const float4*)(ws2);
                *(float4*)&ldsB[srow][scol + 4] = *(const float4*)(ws2 + 4);
            }
            __syncthreads();
#pragma unroll
            for (int hh = 0; hh < FHC; ++hh) {
                float a0 = ldsA[t0][hh], a1 = ldsA[t1][hh];
                const float4 b4 = *(const float4*)&ldsB[hh][sg4 * 4];
                yacc[0][dt * 4 + 0] = fmaf(a0, b4.x, yacc[0][dt * 4 + 0]);
                yacc[0][dt * 4 + 1] = fmaf(a0, b4.y, yacc[0][dt * 4 + 1]);
                yacc[0][dt * 4 + 2] = fmaf(a0, b4.z, yacc[0][dt * 4 + 2]);
                yacc[0][dt * 4 + 3] = fmaf(a0, b4.w, yacc[0][dt * 4 + 3]);
                yacc[1][dt * 4 + 0] = fmaf(a1, b4.x, yacc[1][dt * 4 + 0]);
                yacc[1][dt * 4 + 1] = fmaf(a1, b4.y, yacc[1][dt * 4 + 1]);
                yacc[1][dt * 4 + 2] = fmaf(a1, b4.z, yacc[1][dt * 4 + 2]);
                yacc[1][dt * 4 + 3] = fmaf(a1, b4.w, yacc[1][dt * 4 + 3]);
            }
        }
    }
    const float* b2e = b2 + (size_t)e * D_DIM;
#pragma unroll
    for (int p = 0; p < 2; ++p) {
        int slot = (p == 0) ? t0 : t1;
        if (tile * FBT + slot < cnt) {
            float wv = tw[slot];
            float* op = out + (size_t)toks[slot] * D_DIM;
#pragma unroll
            for (int dt = 0; dt < 8; ++dt)
#pragma unroll
                for (int j = 0; j < 4; ++j) {
                    int d = dt * 64 + sg4 * 4 + j;
                    atomicAdd(&op[d], wv * (yacc[p][dt * 4 + j] + b2e[d]));
                }
        }
    }
}

// ===========================================================================
extern "C" void kernel_launch(void* const* d_in, const int* in_sizes, int n_in,
                              void* d_out, int out_size, void* d_ws, size_t ws_size,
                              hipStream_t stream) {
    const float* x  = (const float*)d_in[0];
    const float* Wr = (const float*)d_in[1];
    const float* W1 = (const float*)d_in[2];
    const float* b1 = (const float*)d_in[3];
    const float* W2 = (const float*)d_in[4];
    const float* b2 = (const float*)d_in[5];
    float* out = (float*)d_out;
    int ntok = in_sizes[0] / D_DIM;   // 16384

    size_t off_route = 1024;
    size_t off_gate  = off_route + (size_t)ntok * 4;
    size_t off_lists = off_gate + (size_t)2 * ntok * 4;
    size_t off_xb    = off_lists + (size_t)NEXP * ntok * 4;
    size_t off_w1t   = off_xb + (size_t)ntok * D_DIM * 2;
    size_t off_w2t   = off_w1t + (size_t)NEXP * D_DIM * H_DIM * 2;
    size_t off_hdn   = off_w2t + (size_t)NEXP * D_DIM * H_DIM * 2;
    size_t need      = off_hdn + (size_t)(2 * ntok + 256) * H_DIM * 2;  // +slack

    int*   cb     = (int*)d_ws;
    int*   route  = (int*)((char*)d_ws + off_route);
    float* gate_w = (float*)((char*)d_ws + off_gate);
    int*   lists  = (int*)((char*)d_ws + off_lists);

    if (ws_size >= need) {
        unsigned short* xb  = (unsigned short*)((char*)d_ws + off_xb);
        unsigned short* W1T = (unsigned short*)((char*)d_ws + off_w1t);
        unsigned short* W2T = (unsigned short*)((char*)d_ws + off_w2t);
        unsigned short* hdn = (unsigned short*)((char*)d_ws + off_hdn);

        transpose_conv_kernel<<<dim3(H_DIM / 64, D_DIM / 64, NEXP), 256, 0, stream>>>(
            W1, W1T, D_DIM, H_DIM);
        transpose_conv_kernel<<<dim3(D_DIM / 64, H_DIM / 64, NEXP), 256, 0, stream>>>(
            W2, W2T, H_DIM, D_DIM);
        router_kernel<<<(ntok + 3) / 4, 256, 0, stream>>>(
            x, Wr, gate_w, route, xb, ntok);
        lists_kernel<<<NEXP, 256, 0, stream>>>(route, lists, cb, ntok);
        prefix_kernel<<<1, 64, 0, stream>>>(cb);
        bias_gate_kernel<<<(ntok + 3) / 4, 256, 0, stream>>>(
            route, gate_w, b2, out, ntok);
        int mtiles = ntok / 128;   // 128
        gemm1_kernel<<<NEXP * 16 * mtiles, 256, 0, stream>>>(
            xb, W1T, b1, gate_w, lists, cb, hdn, ntok);
        gemm2_kernel<<<NEXP * 4 * mtiles, 256, 0, stream>>>(
            hdn, W2T, lists, cb, out, ntok);
    } else {
        hipMemsetAsync(d_out, 0, (size_t)out_size * sizeof(float), stream);
        router_kernel<<<(ntok + 3) / 4, 256, 0, stream>>>(
            x, Wr, gate_w, route, (unsigned short*)0, ntok);
        lists_kernel<<<NEXP, 256, 0, stream>>>(route, lists, cb, ntok);
        prefix_kernel<<<1, 64, 0, stream>>>(cb);
        int tiles = (ntok + FBT - 1) / FBT;
        moe_fused_fallback<<<NEXP * tiles, FTPB, 0, stream>>>(
            x, W1, b1, W2, b2, gate_w, lists, cb, out, ntok, tiles);
    }
}